// Round 15
// baseline (652.739 us; speedup 1.0000x reference)
//
#include <hip/hip_runtime.h>
#include <hip/hip_bf16.h>

// GraphConvLayer: out = relu(A_norm @ (X@W + b))
// R15 = R14 (Xf-prepack dense two-GEMM, 599us) + two levers:
//  1. RPB=128 (5 tiles/bt): each staged X chunk feeds 2x MFMAs -> staging
//     traffic per output halved, arithmetic intensity doubled.
//  2. 32-row sub-chunk double-buffer with counted waits: loads for s+1 in
//     flight across phase s (raw s_barrier, no vmcnt drain-then-load).
// GEMM2 + epilogue in two 64-row halves (Y-half overlays dead XF buffers).

#define NND    543
#define BTOT   1024
#define NTIL   5
#define RPB    128
#define NCH    9            // 64-row chunks in Xf layout
#define NSC    17           // 32-row sub-chunks actually processed
#define GRID2  (BTOT*NTIL)  // 5120, %8==0
#define GRIDB  (BTOT*9)     // bare fallback grid

typedef __attribute__((ext_vector_type(8))) short short8;
typedef __attribute__((ext_vector_type(4))) float f32x4;

// ---- workspace ----
#define XF_BYTES ((size_t)BTOT*NCH*2048*16)   // 301,989,888 [bt][c][ (fg*2+ks)*64+lane ][16B]
#define MT_A2    0                            // bf16 A-frags [tile5][c9][ks2][mt8][lane64][16B] = 737280
#define MT_W     737280                       // bf16 W-frags [g16][ks8][lane64][16B] = 131072
#define MT_RS    868352                       // f32[640]
#define MT_BYTES 870912
#define WS_BIG   (XF_BYTES + (size_t)MT_BYTES)

// ---- LDS (bytes), main ----
#define LXF0 0              // XF sub-chunk buf0 16KB
#define LXF1 16384          // buf1
#define LA0  32768          // A sub-chunk buf0 8KB
#define LA1  40960          // buf1
#define LRS  49152          // f32[128]
#define LTOT 49664          // 48.5KB -> 2 blocks/CU
// After K-loop: Y bf16 [64][512B] overlays [0,32768); bounce overlays [0,18432).

#define GLD16(G, Ld) __builtin_amdgcn_global_load_lds( \
    (const __attribute__((address_space(1))) void*)(G), \
    (__attribute__((address_space(3))) void*)(Ld), 16, 0, 0)

__device__ __forceinline__ unsigned short f2bf(float f) {   // RNE f32 -> bf16 bits
  unsigned int u = __builtin_bit_cast(unsigned int, f);
  u += 0x7fffu + ((u >> 16) & 1u);
  return (unsigned short)(u >> 16);
}

// ---------------- prep: X -> bf16 B-fragment layout (unchanged from R14) ----------------
__global__ void prep_xf(const float* __restrict__ x, char* __restrict__ xf) {
  __shared__ __align__(16) char xl[64 * 512];
  const int bc = blockIdx.x;                           // bt*NCH + c
  const int bt = bc / NCH, c = bc - bt * NCH;
  const int tid = threadIdx.x;                         // 256
  const float* xbt = x + (size_t)bt * (NND * 256);
  #pragma unroll
  for (int it = 0; it < 16; ++it) {
    const int slot = tid + (it << 8);
    const int r = slot >> 6, f4 = slot & 63;
    const int m = c * 64 + r;
    float4 v = make_float4(0.f, 0.f, 0.f, 0.f);
    if (m < NND) v = *(const float4*)(xbt + ((size_t)m << 8) + (f4 << 2));
    uint2 u;
    u.x = (unsigned)f2bf(v.x) | ((unsigned)f2bf(v.y) << 16);
    u.y = (unsigned)f2bf(v.z) | ((unsigned)f2bf(v.w) << 16);
    *(uint2*)(xl + (r << 9) + (f4 << 3)) = u;
  }
  __syncthreads();
  unsigned short* dst = (unsigned short*)xf + ((size_t)bc << 14);
  const unsigned short* src = (const unsigned short*)xl;
  #pragma unroll
  for (int it = 0; it < 8; ++it) {
    const int fi = tid + (it << 8);
    const int lane = fi & 63, ks = (fi >> 6) & 1, fg = fi >> 7;
    const int kl = ks * 32 + (lane >> 4) * 8;
    const int n = fg * 16 + (lane & 15);
    unsigned short tmp[8];
    #pragma unroll
    for (int e = 0; e < 8; ++e) tmp[e] = src[(kl + e) * 256 + n];
    *(uint4*)(dst + (size_t)fi * 8) = *(const uint4*)tmp;
  }
}

// ---------------- prep: A -> bf16 A-frags [tile][c][ks][mt][lane][8] (RPB=128) ----------------
__global__ void prep_a2(const float* __restrict__ A, char* __restrict__ meta) {
  const int t = blockIdx.x * 256 + threadIdx.x;
  if (t >= NTIL * NCH * 2 * 8 * 64) return;            // 46080
  const int lane = t & 63;
  const int mt = (t >> 6) & 7;
  const int ks = (t >> 9) & 1;
  const int c = (t >> 10) % NCH;
  const int tile = (t >> 10) / NCH;
  const int m = tile * RPB + mt * 16 + (lane & 15);
  const int kb = c * 64 + ks * 32 + (lane >> 4) * 8;
  unsigned short* dst = (unsigned short*)(meta + MT_A2) + (size_t)t * 8;
  #pragma unroll
  for (int e = 0; e < 8; ++e) {
    const int k = kb + e;
    dst[e] = (m < NND && k < NND) ? f2bf(A[(size_t)m * NND + k]) : (unsigned short)0;
  }
}

// ---------------- prep: W -> bf16 B-frags (unchanged) ----------------
__global__ void prep_w(const float* __restrict__ W, char* __restrict__ meta) {
  const int t = blockIdx.x * 256 + threadIdx.x;
  if (t >= 16 * 8 * 64) return;
  const int lane = t & 63, ks = (t >> 6) & 7, g = t >> 9;
  const int krow = (lane >> 4) * 8, col = g * 16 + (lane & 15);
  unsigned short* dst = (unsigned short*)(meta + MT_W) + (size_t)t * 8;
  #pragma unroll
  for (int e = 0; e < 8; e++) dst[e] = f2bf(W[(ks * 32 + krow + e) * 256 + col]);
}

// ---------------- prep: rowsum ----------------
__global__ void prep_rs(const float* __restrict__ A, char* __restrict__ meta) {
  const int wid = (blockIdx.x * blockDim.x + threadIdx.x) >> 6;
  const int lane = threadIdx.x & 63;
  if (wid >= NTIL * RPB) return;
  float s = 0.f;
  if (wid < NND) {
    const float* arow = A + (size_t)wid * NND;
    for (int m = lane; m < NND; m += 64) s += arow[m];
  }
  #pragma unroll
  for (int o = 32; o > 0; o >>= 1) s += __shfl_xor(s, o);
  if (lane == 0) ((float*)(meta + MT_RS))[wid] = s;
}

// ---------------- main (mode 2) ----------------
__global__ __launch_bounds__(512, 2)
void gcn_main(const float* __restrict__ bias, float* __restrict__ out,
              const char* __restrict__ xfb, const char* __restrict__ meta)
{
  __shared__ __align__(16) char lds[LTOT];
  float* rsl = (float*)(lds + LRS);

  const int tid = threadIdx.x;
  const int w = tid >> 6, lane = tid & 63;
  const int cl = lane & 15, krow = (lane >> 4) * 8;

  const int p = blockIdx.x;
  const int L = (p & 7) * (GRID2 / 8) + (p >> 3);
  const int bt = L / NTIL;
  const int tile = L - bt * NTIL;
  const int n0 = tile * RPB;

  if (tid < RPB) rsl[tid] = ((const float*)(meta + MT_RS))[n0 + tid];

  f32x4 acc[16];
  #pragma unroll
  for (int i = 0; i < 16; ++i) acc[i] = (f32x4){0.f, 0.f, 0.f, 0.f};

  const size_t xck = ((size_t)bt * NCH) << 15;     // 32KB per (bt,c)

  // issue sub-chunk S into parity buffer PB (3 GLD16/wave: 2 X-fg + 1 A-mt)
#define ISSUE(S, PB) { \
    const int c_ = (S) >> 1, ks_ = (S) & 1; \
    const char* xc_ = xfb + xck + ((size_t)c_ << 15) + (ks_ << 10); \
    GLD16(xc_ + ((2 * w + 0) << 11) + (lane << 4), lds + ((PB) << 14) + ((2 * w + 0) << 10)); \
    GLD16(xc_ + ((2 * w + 1) << 11) + (lane << 4), lds + ((PB) << 14) + ((2 * w + 1) << 10)); \
    const char* ac_ = meta + MT_A2 + ((size_t)(((tile * NCH + c_) << 1) + ks_) << 13); \
    GLD16(ac_ + (w << 10) + (lane << 4), lds + LA0 + ((PB) << 13) + (w << 10)); }

  ISSUE(0, 0);
  #pragma unroll 1
  for (int s = 0; s < NSC; ++s) {
    asm volatile("s_waitcnt vmcnt(0)" ::: "memory");  // own sub-s loads complete
    __builtin_amdgcn_s_barrier();                     // everyone's complete; prev parity free
    __builtin_amdgcn_sched_barrier(0);
    if (s + 1 < NSC) ISSUE(s + 1, (s + 1) & 1);       // in flight across this phase
    __builtin_amdgcn_sched_barrier(0);

    const char* xb = lds + ((s & 1) << 14);
    const char* ab = lds + LA0 + ((s & 1) << 13);
    const short8 xf0 = *(const short8*)(xb + ((2 * w + 0) << 10) + (lane << 4));
    const short8 xf1 = *(const short8*)(xb + ((2 * w + 1) << 10) + (lane << 4));
    {                                                 // mt group 0..3
      const short8 a0 = *(const short8*)(ab + (0 << 10) + (lane << 4));
      const short8 a1 = *(const short8*)(ab + (1 << 10) + (lane << 4));
      const short8 a2 = *(const short8*)(ab + (2 << 10) + (lane << 4));
      const short8 a3 = *(const short8*)(ab + (3 << 10) + (lane << 4));
      acc[0] = __builtin_amdgcn_mfma_f32_16x16x32_bf16(a0, xf0, acc[0], 0, 0, 0);
      acc[1] = __builtin_amdgcn_mfma_f32_16x16x32_bf16(a0, xf1, acc[1], 0, 0, 0);
      acc[2] = __builtin_amdgcn_mfma_f32_16x16x32_bf16(a1, xf0, acc[2], 0, 0, 0);
      acc[3] = __builtin_amdgcn_mfma_f32_16x16x32_bf16(a1, xf1, acc[3], 0, 0, 0);
      acc[4] = __builtin_amdgcn_mfma_f32_16x16x32_bf16(a2, xf0, acc[4], 0, 0, 0);
      acc[5] = __builtin_amdgcn_mfma_f32_16x16x32_bf16(a2, xf1, acc[5], 0, 0, 0);
      acc[6] = __builtin_amdgcn_mfma_f32_16x16x32_bf16(a3, xf0, acc[6], 0, 0, 0);
      acc[7] = __builtin_amdgcn_mfma_f32_16x16x32_bf16(a3, xf1, acc[7], 0, 0, 0);
    }
    {                                                 // mt group 4..7
      const short8 a4 = *(const short8*)(ab + (4 << 10) + (lane << 4));
      const short8 a5 = *(const short8*)(ab + (5 << 10) + (lane << 4));
      const short8 a6 = *(const short8*)(ab + (6 << 10) + (lane << 4));
      const short8 a7 = *(const short8*)(ab + (7 << 10) + (lane << 4));
      acc[8]  = __builtin_amdgcn_mfma_f32_16x16x32_bf16(a4, xf0, acc[8],  0, 0, 0);
      acc[9]  = __builtin_amdgcn_mfma_f32_16x16x32_bf16(a4, xf1, acc[9],  0, 0, 0);
      acc[10] = __builtin_amdgcn_mfma_f32_16x16x32_bf16(a5, xf0, acc[10], 0, 0, 0);
      acc[11] = __builtin_amdgcn_mfma_f32_16x16x32_bf16(a5, xf1, acc[11], 0, 0, 0);
      acc[12] = __builtin_amdgcn_mfma_f32_16x16x32_bf16(a6, xf0, acc[12], 0, 0, 0);
      acc[13] = __builtin_amdgcn_mfma_f32_16x16x32_bf16(a6, xf1, acc[13], 0, 0, 0);
      acc[14] = __builtin_amdgcn_mfma_f32_16x16x32_bf16(a7, xf0, acc[14], 0, 0, 0);
      acc[15] = __builtin_amdgcn_mfma_f32_16x16x32_bf16(a7, xf1, acc[15], 0, 0, 0);
    }
  }
#undef ISSUE
  __syncthreads();                                    // all MFMA reads done; XF region reusable

  // ======== GEMM2 + epilogue in two 64-row halves ========
  const char* wbase = meta + MT_W;
  const int gA = 2 * w;
  const int dA = w * 32 + cl;
  const float bvA = bias[dA], bvB = bias[dA + 16];

  #pragma unroll
  for (int h = 0; h < 2; ++h) {
    // Y-half -> LDS bf16 [64][512B], XOR-swizzled (overlays XF buffers)
    #pragma unroll
    for (int mt = 0; mt < 4; ++mt)
      #pragma unroll
      for (int nt = 0; nt < 2; ++nt)
        #pragma unroll
        for (int q = 0; q < 4; ++q) {
          const int row = mt * 16 + (lane >> 4) * 4 + q;   // C/D: col=lane&15, row=(lane>>4)*4+q
          const int col = w * 32 + nt * 16 + cl;
          *(unsigned short*)(lds + row * 512 + ((col * 2) ^ ((row & 7) << 4))) =
              f2bf(acc[(h * 4 + mt) * 2 + nt][q]);
        }
    __syncthreads();

    // GEMM2 half: out rows h*64.. ; W-frags streamed cur/next
    f32x4 aA[4], aB[4];
    #pragma unroll
    for (int mt = 0; mt < 4; ++mt) {
      aA[mt] = (f32x4){0.f, 0.f, 0.f, 0.f};
      aB[mt] = (f32x4){0.f, 0.f, 0.f, 0.f};
    }
    short8 wA = *(const short8*)(wbase + (size_t)(((gA * 8 + 0) * 64 + lane) << 4));
    short8 wB = *(const short8*)(wbase + (size_t)((((gA + 1) * 8 + 0) * 64 + lane) << 4));
    #pragma unroll
    for (int ks = 0; ks < 8; ++ks) {
      short8 wAn = wA, wBn = wB;
      if (ks < 7) {
        wAn = *(const short8*)(wbase + (size_t)(((gA * 8 + ks + 1) * 64 + lane) << 4));
        wBn = *(const short8*)(wbase + (size_t)((((gA + 1) * 8 + ks + 1) * 64 + lane) << 4));
      }
      #pragma unroll
      for (int mt = 0; mt < 4; ++mt) {
        const int r = mt * 16 + cl;
        const int kb = (ks * 64 + krow * 2) ^ ((r & 7) << 4);
        const short8 af = *(const short8*)(lds + r * 512 + kb);
        aA[mt] = __builtin_amdgcn_mfma_f32_16x16x32_bf16(af, wA, aA[mt], 0, 0, 0);
        aB[mt] = __builtin_amdgcn_mfma_f32_16x16x32_bf16(af, wB, aB[mt], 0, 0, 0);
      }
      wA = wAn; wB = wBn;
    }
    __syncthreads();                                  // done reading Y half

    // epilogue half: bias+relu -> per-wave bounce -> full-line dwordx4 stores
    float* wb = (float*)lds + w * (16 * 36);          // overlays dead Y rows
    #pragma unroll
    for (int mt = 0; mt < 4; ++mt) {
      #pragma unroll
      for (int q = 0; q < 4; ++q) {
        const int r16 = (lane >> 4) * 4 + q;
        const float rsv = rsl[h * 64 + mt * 16 + r16];
        wb[r16 * 36 + cl]      = fmaxf(aA[mt][q] + rsv * bvA, 0.f);
        wb[r16 * 36 + 16 + cl] = fmaxf(aB[mt][q] + rsv * bvB, 0.f);
      }
      asm volatile("s_waitcnt lgkmcnt(0)" ::: "memory");   // per-wave private region
      #pragma unroll
      for (int v = 0; v < 2; ++v) {
        const int i = lane * 2 + v;
        const int rI = i >> 3, cv = i & 7;
        const int n = n0 + h * 64 + mt * 16 + rI;
        if (n < NND)
          *(f32x4*)(out + ((size_t)bt * NND + n) * 256 + w * 32 + cv * 4) =
              *(const f32x4*)(wb + rI * 36 + cv * 4);
      }
    }
    if (h == 0) __syncthreads();                      // bounce region becomes Y half1
  }
}

// ---------------- bare fallback (no workspace): dense gather + on-the-fly W ----------------
__global__ __launch_bounds__(512, 2)
void gcn_bare(const float* __restrict__ x, const float* __restrict__ Wm,
              const float* __restrict__ bias, const float* __restrict__ A,
              float* __restrict__ out)
{
  __shared__ __align__(16) char lds[33280];           // Y 32KB + rsl
  float* rsl = (float*)(lds + 32768);
  const int tid = threadIdx.x;
  const int w = tid >> 6, lane = tid & 63;
  const int cl = lane & 15, krow = (lane >> 4) * 8;
  const int p = blockIdx.x;
  const int L = (p & 7) * (GRIDB / 8) + (p >> 3);
  const int bt = L / 9;
  const int tile = L - bt * 9;
  const int n0 = tile * 64;
  const float* xbt = x + (size_t)bt * (NND * 256);

  for (int i = 0; i < 8; ++i) {
    const int r = w * 8 + i;
    const int n = n0 + r;
    f32x4 yv = (f32x4){0.f, 0.f, 0.f, 0.f};
    float s = 0.f;
    if (n < NND) {
      const float* arow = A + (size_t)n * NND;
      for (int m = 0; m < NND; ++m) {
        const float a = arow[m];
        s += a;
        if (a != 0.f) yv += a * *(const f32x4*)(xbt + (m << 8) + (lane << 2));
      }
    }
    if (lane == 0) rsl[r] = s;
    uint2 u;
    u.x = (unsigned)f2bf(yv.x) | ((unsigned)f2bf(yv.y) << 16);
    u.y = (unsigned)f2bf(yv.z) | ((unsigned)f2bf(yv.w) << 16);
    *(uint2*)(lds + r * 512 + ((lane * 8) ^ ((r & 7) << 4))) = u;
  }
  __syncthreads();

  const int gA = 2 * w;
  short8 wfA[8], wfB[8];
  #pragma unroll
  for (int ks = 0; ks < 8; ++ks)
    #pragma unroll
    for (int e = 0; e < 8; ++e) {
      wfA[ks][e] = (short)f2bf(Wm[(ks * 32 + krow + e) * 256 + gA * 16 + cl]);
      wfB[ks][e] = (short)f2bf(Wm[(ks * 32 + krow + e) * 256 + (gA + 1) * 16 + cl]);
    }
  f32x4 aA[4], aB[4];
  #pragma unroll
  for (int mt = 0; mt < 4; ++mt) {
    aA[mt] = (f32x4){0.f, 0.f, 0.f, 0.f};
    aB[mt] = (f32x4){0.f, 0.f, 0.f, 0.f};
  }
  #pragma unroll
  for (int ks = 0; ks < 8; ++ks)
    #pragma unroll
    for (int mt = 0; mt < 4; ++mt) {
      const int r = mt * 16 + cl;
      const int kb = (ks * 64 + krow * 2) ^ ((r & 7) << 4);
      const short8 af = *(const short8*)(lds + r * 512 + kb);
      aA[mt] = __builtin_amdgcn_mfma_f32_16x16x32_bf16(af, wfA[ks], aA[mt], 0, 0, 0);
      aB[mt] = __builtin_amdgcn_mfma_f32_16x16x32_bf16(af, wfB[ks], aB[mt], 0, 0, 0);
    }
  __syncthreads();

  float* wb = (float*)lds + w * (16 * 36);
  const int dA = w * 32 + cl;
  const float bvA = bias[dA], bvB = bias[dA + 16];
  #pragma unroll
  for (int mt = 0; mt < 4; ++mt) {
    #pragma unroll
    for (int q = 0; q < 4; ++q) {
      const int r16 = (lane >> 4) * 4 + q;
      const float rsv = rsl[mt * 16 + r16];
      wb[r16 * 36 + cl]      = fmaxf(aA[mt][q] + rsv * bvA, 0.f);
      wb[r16 * 36 + 16 + cl] = fmaxf(aB[mt][q] + rsv * bvB, 0.f);
    }
    asm volatile("s_waitcnt lgkmcnt(0)" ::: "memory");
    #pragma unroll
    for (int v = 0; v < 2; ++v) {
      const int i = lane * 2 + v;
      const int rI = i >> 3, cv = i & 7;
      const int n = n0 + mt * 16 + rI;
      if (n < NND)
        *(f32x4*)(out + ((size_t)bt * NND + n) * 256 + w * 32 + cv * 4) =
            *(const f32x4*)(wb + rI * 36 + cv * 4);
    }
  }
}

extern "C" void kernel_launch(void* const* d_in, const int* in_sizes, int n_in,
                              void* d_out, int out_size, void* d_ws, size_t ws_size,
                              hipStream_t stream) {
  const float* x  = (const float*)d_in[0];
  const float* Wm = (const float*)d_in[1];
  const float* b  = (const float*)d_in[2];
  const float* A  = (const float*)d_in[3];
  float* out = (float*)d_out;
  if (d_ws && ws_size >= WS_BIG) {
    char* xfp  = (char*)d_ws;
    char* meta = (char*)d_ws + XF_BYTES;
    prep_a2<<<(NTIL * NCH * 2 * 8 * 64 + 255) / 256, 256, 0, stream>>>(A, meta);
    prep_w<<<(16 * 8 * 64 + 255) / 256, 256, 0, stream>>>(Wm, meta);
    prep_rs<<<(NTIL * RPB * 64 + 255) / 256, 256, 0, stream>>>(A, meta);
    prep_xf<<<BTOT * NCH, 256, 0, stream>>>(x, xfp);
    gcn_main<<<GRID2, 512, 0, stream>>>(b, out, xfp, meta);
  } else {
    gcn_bare<<<GRIDB, 512, 0, stream>>>(x, Wm, b, A, out);
  }
}

// Round 16
// 573.121 us; speedup vs baseline: 1.1389x; 1.1389x over previous
//
#include <hip/hip_runtime.h>
#include <hip/hip_bf16.h>

// GraphConvLayer: out = relu(A_norm @ (X@W + b))
// R16 = R14 skeleton (RPB=64, Xf prepack, 2 blocks/CU) with the GEMM1 K-loop
// restructured for overlap:
//  - X fragments loaded DIRECTLY global->VGPR (lane-contiguous by prepack
//    construction; no LDS, no barrier coupling), double-buffered in registers
//    across chunks (full unroll -> SSA, no dynamic indexing).
//  - A fragments (shared by all 8 waves) via LDS, double-buffered GLD16.
//  - Phase: vmcnt(0) [covers loads issued one full phase earlier] -> raw
//    s_barrier -> issue c+1 (X-to-reg + A-GLD16) -> sched_barrier -> MFMA.
// R15 lesson honored: acc stays at 8 f32x4 (32 AGPR) -> true reg use < 128.

#define NND    543
#define RPB    64
#define NTILES 9
#define NCH    9
#define BTOT   1024
#define GRID   (BTOT*NTILES)   // 9216, %8==0 -> bijective XCD swizzle

typedef __attribute__((ext_vector_type(8))) short short8;
typedef __attribute__((ext_vector_type(4))) float f32x4;

// ---- workspace ----
#define XF_BYTES ((size_t)BTOT*NCH*2048*16)   // 301,989,888 [bt][c][(fg*2+ks)*64+lane][16B]
#define MT_A     0                            // bf16 A-frags [tile9][c9][f8][lane64][16B] = 663552
#define MT_W     663552                       // bf16 W-frags [g16][ks8][lane64][16B] = 131072
#define MT_RS    794624                       // f32[576]
#define MT_BYTES 797184
#define WS_BIG   (XF_BYTES + (size_t)MT_BYTES)

// ---- LDS (bytes), main ----
#define LA0   0             // A chunk buf0 8KB
#define LA1   8192          // buf1
// post K-loop: Y bf16 [64][512B] = 32KB overlays [0,32768); bounce overlays [0,18432)
#define LRS   32768         // f32[64]
#define LTOT  33280         // 32.5KB -> 2 blocks/CU easily

#define GLD16(G, Ld) __builtin_amdgcn_global_load_lds( \
    (const __attribute__((address_space(1))) void*)(G), \
    (__attribute__((address_space(3))) void*)(Ld), 16, 0, 0)

__device__ __forceinline__ unsigned short f2bf(float f) {   // RNE f32 -> bf16 bits
  unsigned int u = __builtin_bit_cast(unsigned int, f);
  u += 0x7fffu + ((u >> 16) & 1u);
  return (unsigned short)(u >> 16);
}

// ---------------- prep: X -> bf16 B-fragment layout (unchanged, proven R14) ----------------
__global__ void prep_xf(const float* __restrict__ x, char* __restrict__ xf) {
  __shared__ __align__(16) char xl[64 * 512];
  const int bc = blockIdx.x;                           // bt*NCH + c
  const int bt = bc / NCH, c = bc - bt * NCH;
  const int tid = threadIdx.x;                         // 256
  const float* xbt = x + (size_t)bt * (NND * 256);
  #pragma unroll
  for (int it = 0; it < 16; ++it) {
    const int slot = tid + (it << 8);
    const int r = slot >> 6, f4 = slot & 63;
    const int m = c * 64 + r;
    float4 v = make_float4(0.f, 0.f, 0.f, 0.f);
    if (m < NND) v = *(const float4*)(xbt + ((size_t)m << 8) + (f4 << 2));
    uint2 u;
    u.x = (unsigned)f2bf(v.x) | ((unsigned)f2bf(v.y) << 16);
    u.y = (unsigned)f2bf(v.z) | ((unsigned)f2bf(v.w) << 16);
    *(uint2*)(xl + (r << 9) + (f4 << 3)) = u;
  }
  __syncthreads();
  unsigned short* dst = (unsigned short*)xf + ((size_t)bc << 14);
  const unsigned short* src = (const unsigned short*)xl;
  #pragma unroll
  for (int it = 0; it < 8; ++it) {
    const int fi = tid + (it << 8);
    const int lane = fi & 63, ks = (fi >> 6) & 1, fg = fi >> 7;
    const int kl = ks * 32 + (lane >> 4) * 8;
    const int n = fg * 16 + (lane & 15);
    unsigned short tmp[8];
    #pragma unroll
    for (int e = 0; e < 8; ++e) tmp[e] = src[(kl + e) * 256 + n];
    *(uint4*)(dst + (size_t)fi * 8) = *(const uint4*)tmp;
  }
}

// ---------------- prep: A -> bf16 A-frags [tile][c][f=mt*2+ks][lane][16B] ----------------
__global__ void prep_a(const float* __restrict__ A, char* __restrict__ meta) {
  const int t = blockIdx.x * 256 + threadIdx.x;
  if (t >= NTILES * NCH * 8 * 64) return;
  const int lane = t & 63;
  const int f = (t >> 6) & 7;
  const int c = (t >> 9) % NCH;
  const int tile = t / (NCH * 8 * 64);
  const int mt = f >> 1, ks = f & 1;
  const int m = tile * 64 + mt * 16 + (lane & 15);
  const int kb = c * 64 + ks * 32 + (lane >> 4) * 8;
  unsigned short* dst = (unsigned short*)(meta + MT_A) + (size_t)t * 8;
  #pragma unroll
  for (int e = 0; e < 8; ++e) {
    const int k = kb + e;
    dst[e] = (m < NND && k < NND) ? f2bf(A[(size_t)m * NND + k]) : (unsigned short)0;
  }
}

// ---------------- prep: W -> bf16 B-frags ----------------
__global__ void prep_w(const float* __restrict__ W, char* __restrict__ meta) {
  const int t = blockIdx.x * 256 + threadIdx.x;
  if (t >= 16 * 8 * 64) return;
  const int lane = t & 63, ks = (t >> 6) & 7, g = t >> 9;
  const int krow = (lane >> 4) * 8, col = g * 16 + (lane & 15);
  unsigned short* dst = (unsigned short*)(meta + MT_W) + (size_t)t * 8;
  #pragma unroll
  for (int e = 0; e < 8; e++) dst[e] = f2bf(W[(ks * 32 + krow + e) * 256 + col]);
}

// ---------------- prep: rowsum ----------------
__global__ void prep_rs(const float* __restrict__ A, char* __restrict__ meta) {
  const int wid = (blockIdx.x * blockDim.x + threadIdx.x) >> 6;
  const int lane = threadIdx.x & 63;
  if (wid >= NTILES * RPB) return;
  float s = 0.f;
  if (wid < NND) {
    const float* arow = A + (size_t)wid * NND;
    for (int m = lane; m < NND; m += 64) s += arow[m];
  }
  #pragma unroll
  for (int o = 32; o > 0; o >>= 1) s += __shfl_xor(s, o);
  if (lane == 0) ((float*)(meta + MT_RS))[wid] = s;
}

// ---------------- main ----------------
__global__ __launch_bounds__(512, 2)
void gcn_main(const float* __restrict__ bias, float* __restrict__ out,
              const char* __restrict__ xfb, const char* __restrict__ meta)
{
  __shared__ __align__(16) char lds[LTOT];
  float* rsl = (float*)(lds + LRS);

  const int tid = threadIdx.x;
  const int w = tid >> 6, lane = tid & 63;
  const int cl = lane & 15, krow = (lane >> 4) * 8;

  const int p = blockIdx.x;
  const int L = (p & 7) * (GRID / 8) + (p >> 3);
  const int bt = L / NTILES;
  const int tile = L - bt * NTILES;
  const int n0 = tile * RPB;

  if (tid < RPB) rsl[tid] = ((const float*)(meta + MT_RS))[n0 + tid];

  // ======== GEMM1: Y = A_tile @ X ; X frags direct-to-reg, A frags via LDS dbuf ========
  f32x4 acc[8];
  #pragma unroll
  for (int i = 0; i < 8; ++i) acc[i] = (f32x4){0.f, 0.f, 0.f, 0.f};

  const size_t xbase = ((size_t)(bt * NCH)) << 15;     // 32KB per (bt,c)
  const int xo00 = (((2 * w + 0) * 2 + 0) * 64 + lane) << 4;   // nt0 ks0
  const int xo01 = (((2 * w + 0) * 2 + 1) * 64 + lane) << 4;   // nt0 ks1
  const int xo10 = (((2 * w + 1) * 2 + 0) * 64 + lane) << 4;   // nt1 ks0
  const int xo11 = (((2 * w + 1) * 2 + 1) * 64 + lane) << 4;   // nt1 ks1
  const char* abase = meta + MT_A + ((size_t)(tile * NCH) << 13);  // 8KB per chunk

  // prologue: chunk 0 in flight
  const char* x0 = xfb + xbase;
  short8 xc00 = *(const short8*)(x0 + xo00);
  short8 xc01 = *(const short8*)(x0 + xo01);
  short8 xc10 = *(const short8*)(x0 + xo10);
  short8 xc11 = *(const short8*)(x0 + xo11);
  GLD16(abase + (w << 10) + (lane << 4), lds + LA0 + (w << 10));

  #pragma unroll
  for (int c = 0; c < NCH; ++c) {
    asm volatile("s_waitcnt vmcnt(0)" ::: "memory");   // chunk-c X & A complete
    __builtin_amdgcn_s_barrier();                      // everyone's A(c) staged; c-1 parity free
    __builtin_amdgcn_sched_barrier(0);

    short8 xn00, xn01, xn10, xn11;
    if (c + 1 < NCH) {                                 // compile-time (full unroll)
      const char* xn = xfb + xbase + ((size_t)(c + 1) << 15);
      xn00 = *(const short8*)(xn + xo00);
      xn01 = *(const short8*)(xn + xo01);
      xn10 = *(const short8*)(xn + xo10);
      xn11 = *(const short8*)(xn + xo11);
      GLD16(abase + ((size_t)(c + 1) << 13) + (w << 10) + (lane << 4),
            lds + ((c + 1) & 1 ? LA1 : LA0) + (w << 10));
    }
    __builtin_amdgcn_sched_barrier(0);                 // pin issues above the MFMAs

    const char* ab = lds + ((c & 1) ? LA1 : LA0);
    {                                                  // ks = 0
      const short8 a0 = *(const short8*)(ab + ((0 * 2 + 0) << 10) + (lane << 4));
      const short8 a1 = *(const short8*)(ab + ((1 * 2 + 0) << 10) + (lane << 4));
      const short8 a2 = *(const short8*)(ab + ((2 * 2 + 0) << 10) + (lane << 4));
      const short8 a3 = *(const short8*)(ab + ((3 * 2 + 0) << 10) + (lane << 4));
      acc[0] = __builtin_amdgcn_mfma_f32_16x16x32_bf16(a0, xc00, acc[0], 0, 0, 0);
      acc[1] = __builtin_amdgcn_mfma_f32_16x16x32_bf16(a0, xc10, acc[1], 0, 0, 0);
      acc[2] = __builtin_amdgcn_mfma_f32_16x16x32_bf16(a1, xc00, acc[2], 0, 0, 0);
      acc[3] = __builtin_amdgcn_mfma_f32_16x16x32_bf16(a1, xc10, acc[3], 0, 0, 0);
      acc[4] = __builtin_amdgcn_mfma_f32_16x16x32_bf16(a2, xc00, acc[4], 0, 0, 0);
      acc[5] = __builtin_amdgcn_mfma_f32_16x16x32_bf16(a2, xc10, acc[5], 0, 0, 0);
      acc[6] = __builtin_amdgcn_mfma_f32_16x16x32_bf16(a3, xc00, acc[6], 0, 0, 0);
      acc[7] = __builtin_amdgcn_mfma_f32_16x16x32_bf16(a3, xc10, acc[7], 0, 0, 0);
    }
    {                                                  // ks = 1
      const short8 a0 = *(const short8*)(ab + ((0 * 2 + 1) << 10) + (lane << 4));
      const short8 a1 = *(const short8*)(ab + ((1 * 2 + 1) << 10) + (lane << 4));
      const short8 a2 = *(const short8*)(ab + ((2 * 2 + 1) << 10) + (lane << 4));
      const short8 a3 = *(const short8*)(ab + ((3 * 2 + 1) << 10) + (lane << 4));
      acc[0] = __builtin_amdgcn_mfma_f32_16x16x32_bf16(a0, xc01, acc[0], 0, 0, 0);
      acc[1] = __builtin_amdgcn_mfma_f32_16x16x32_bf16(a0, xc11, acc[1], 0, 0, 0);
      acc[2] = __builtin_amdgcn_mfma_f32_16x16x32_bf16(a1, xc01, acc[2], 0, 0, 0);
      acc[3] = __builtin_amdgcn_mfma_f32_16x16x32_bf16(a1, xc11, acc[3], 0, 0, 0);
      acc[4] = __builtin_amdgcn_mfma_f32_16x16x32_bf16(a2, xc01, acc[4], 0, 0, 0);
      acc[5] = __builtin_amdgcn_mfma_f32_16x16x32_bf16(a2, xc11, acc[5], 0, 0, 0);
      acc[6] = __builtin_amdgcn_mfma_f32_16x16x32_bf16(a3, xc01, acc[6], 0, 0, 0);
      acc[7] = __builtin_amdgcn_mfma_f32_16x16x32_bf16(a3, xc11, acc[7], 0, 0, 0);
    }
    xc00 = xn00; xc01 = xn01; xc10 = xn10; xc11 = xn11;   // SSA under full unroll
  }
  __syncthreads();                                     // A-bufs dead; region becomes Y

  // ---- Y -> LDS bf16 [64][512B], XOR-swizzled ----
  #pragma unroll
  for (int mt = 0; mt < 4; ++mt)
    #pragma unroll
    for (int nt = 0; nt < 2; ++nt)
      #pragma unroll
      for (int q = 0; q < 4; ++q) {
        const int row = mt * 16 + (lane >> 4) * 4 + q;   // C/D: col=lane&15, row=(lane>>4)*4+q
        const int col = w * 32 + nt * 16 + cl;
        *(unsigned short*)(lds + row * 512 + ((col * 2) ^ ((row & 7) << 4))) =
            f2bf(acc[mt * 2 + nt][q]);
      }
  __syncthreads();

  // ======== GEMM2: out_tile = relu(Y@W + rs*b); wave w owns cols [w*32, w*32+32) ========
  const char* wbase = meta + MT_W;
  const int gA = 2 * w;
  short8 wfA[8], wfB[8];
  #pragma unroll
  for (int ks = 0; ks < 8; ++ks) {
    wfA[ks] = *(const short8*)(wbase + (size_t)(((gA * 8 + ks) * 64 + lane) << 4));
    wfB[ks] = *(const short8*)(wbase + (size_t)((((gA + 1) * 8 + ks) * 64 + lane) << 4));
  }
  f32x4 aA[4], aB[4];
  #pragma unroll
  for (int mt = 0; mt < 4; ++mt) {
    aA[mt] = (f32x4){0.f, 0.f, 0.f, 0.f};
    aB[mt] = (f32x4){0.f, 0.f, 0.f, 0.f};
  }
  #pragma unroll
  for (int ks = 0; ks < 8; ++ks) {
    #pragma unroll
    for (int mt = 0; mt < 4; ++mt) {
      const int r = mt * 16 + cl;
      const int kb = (ks * 64 + krow * 2) ^ ((r & 7) << 4);
      const short8 af = *(const short8*)(lds + r * 512 + kb);
      aA[mt] = __builtin_amdgcn_mfma_f32_16x16x32_bf16(af, wfA[ks], aA[mt], 0, 0, 0);
      aB[mt] = __builtin_amdgcn_mfma_f32_16x16x32_bf16(af, wfB[ks], aB[mt], 0, 0, 0);
    }
  }
  __syncthreads();   // all waves done reading Y before bounce overlays it

  // ---- epilogue: bias + relu -> per-wave bounce -> full 128B-line dwordx4 stores ----
  float* wb = (float*)lds + w * (16 * 36);
  const int dA = w * 32 + cl;
  const float bvA = bias[dA], bvB = bias[dA + 16];
  #pragma unroll
  for (int mt = 0; mt < 4; ++mt) {
    #pragma unroll
    for (int q = 0; q < 4; ++q) {
      const int r16 = (lane >> 4) * 4 + q;
      const float rsv = rsl[mt * 16 + r16];
      wb[r16 * 36 + cl]      = fmaxf(aA[mt][q] + rsv * bvA, 0.f);
      wb[r16 * 36 + 16 + cl] = fmaxf(aB[mt][q] + rsv * bvB, 0.f);
    }
    asm volatile("s_waitcnt lgkmcnt(0)" ::: "memory");   // per-wave private region
    #pragma unroll
    for (int v = 0; v < 2; ++v) {
      const int i = lane * 2 + v;
      const int rI = i >> 3, cv = i & 7;
      const int n = n0 + mt * 16 + rI;
      if (n < NND)
        *(f32x4*)(out + ((size_t)bt * NND + n) * 256 + w * 32 + cv * 4) =
            *(const f32x4*)(wb + rI * 36 + cv * 4);
    }
  }
}

// ---------------- bare fallback (no workspace) ----------------
__global__ __launch_bounds__(512, 2)
void gcn_bare(const float* __restrict__ x, const float* __restrict__ Wm,
              const float* __restrict__ bias, const float* __restrict__ A,
              float* __restrict__ out)
{
  __shared__ __align__(16) char lds[33280];
  float* rsl = (float*)(lds + 32768);
  const int tid = threadIdx.x;
  const int w = tid >> 6, lane = tid & 63;
  const int cl = lane & 15, krow = (lane >> 4) * 8;
  const int p = blockIdx.x;
  const int L = (p & 7) * (GRID / 8) + (p >> 3);
  const int bt = L / NTILES;
  const int tile = L - bt * NTILES;
  const int n0 = tile * 64;
  const float* xbt = x + (size_t)bt * (NND * 256);

  for (int i = 0; i < 8; ++i) {
    const int r = w * 8 + i;
    const int n = n0 + r;
    f32x4 yv = (f32x4){0.f, 0.f, 0.f, 0.f};
    float s = 0.f;
    if (n < NND) {
      const float* arow = A + (size_t)n * NND;
      for (int m = 0; m < NND; ++m) {
        const float a = arow[m];
        s += a;
        if (a != 0.f) yv += a * *(const f32x4*)(xbt + (m << 8) + (lane << 2));
      }
    }
    if (lane == 0) rsl[r] = s;
    uint2 u;
    u.x = (unsigned)f2bf(yv.x) | ((unsigned)f2bf(yv.y) << 16);
    u.y = (unsigned)f2bf(yv.z) | ((unsigned)f2bf(yv.w) << 16);
    *(uint2*)(lds + r * 512 + ((lane * 8) ^ ((r & 7) << 4))) = u;
  }
  __syncthreads();

  const int gA = 2 * w;
  short8 wfA[8], wfB[8];
  #pragma unroll
  for (int ks = 0; ks < 8; ++ks)
    #pragma unroll
    for (int e = 0; e < 8; ++e) {
      wfA[ks][e] = (short)f2bf(Wm[(ks * 32 + krow + e) * 256 + gA * 16 + cl]);
      wfB[ks][e] = (short)f2bf(Wm[(ks * 32 + krow + e) * 256 + (gA + 1) * 16 + cl]);
    }
  f32x4 aA[4], aB[4];
  #pragma unroll
  for (int mt = 0; mt < 4; ++mt) {
    aA[mt] = (f32x4){0.f, 0.f, 0.f, 0.f};
    aB[mt] = (f32x4){0.f, 0.f, 0.f, 0.f};
  }
  #pragma unroll
  for (int ks = 0; ks < 8; ++ks)
    #pragma unroll
    for (int mt = 0; mt < 4; ++mt) {
      const int r = mt * 16 + cl;
      const int kb = (ks * 64 + krow * 2) ^ ((r & 7) << 4);
      const short8 af = *(const short8*)(lds + r * 512 + kb);
      aA[mt] = __builtin_amdgcn_mfma_f32_16x16x32_bf16(af, wfA[ks], aA[mt], 0, 0, 0);
      aB[mt] = __builtin_amdgcn_mfma_f32_16x16x32_bf16(af, wfB[ks], aB[mt], 0, 0, 0);
    }
  __syncthreads();

  float* wb = (float*)lds + w * (16 * 36);
  const int dA = w * 32 + cl;
  const float bvA = bias[dA], bvB = bias[dA + 16];
  #pragma unroll
  for (int mt = 0; mt < 4; ++mt) {
    #pragma unroll
    for (int q = 0; q < 4; ++q) {
      const int r16 = (lane >> 4) * 4 + q;
      const float rsv = rsl[mt * 16 + r16];
      wb[r16 * 36 + cl]      = fmaxf(aA[mt][q] + rsv * bvA, 0.f);
      wb[r16 * 36 + 16 + cl] = fmaxf(aB[mt][q] + rsv * bvB, 0.f);
    }
    asm volatile("s_waitcnt lgkmcnt(0)" ::: "memory");
    #pragma unroll
    for (int v = 0; v < 2; ++v) {
      const int i = lane * 2 + v;
      const int rI = i >> 3, cv = i & 7;
      const int n = n0 + mt * 16 + rI;
      if (n < NND)
        *(f32x4*)(out + ((size_t)bt * NND + n) * 256 + w * 32 + cv * 4) =
            *(const f32x4*)(wb + rI * 36 + cv * 4);
    }
  }
}

extern "C" void kernel_launch(void* const* d_in, const int* in_sizes, int n_in,
                              void* d_out, int out_size, void* d_ws, size_t ws_size,
                              hipStream_t stream) {
  const float* x  = (const float*)d_in[0];
  const float* Wm = (const float*)d_in[1];
  const float* b  = (const float*)d_in[2];
  const float* A  = (const float*)d_in[3];
  float* out = (float*)d_out;
  if (d_ws && ws_size >= WS_BIG) {
    char* xfp  = (char*)d_ws;
    char* meta = (char*)d_ws + XF_BYTES;
    prep_a<<<(NTILES * NCH * 8 * 64 + 255) / 256, 256, 0, stream>>>(A, meta);
    prep_w<<<(16 * 8 * 64 + 255) / 256, 256, 0, stream>>>(Wm, meta);
    prep_rs<<<(NTILES * RPB * 64 + 255) / 256, 256, 0, stream>>>(A, meta);
    prep_xf<<<BTOT * NCH, 256, 0, stream>>>(x, xfp);
    gcn_main<<<GRID, 512, 0, stream>>>(b, out, xfp, meta);
  } else {
    gcn_bare<<<GRID, 512, 0, stream>>>(x, Wm, b, A, out);
  }
}

// Round 17
// 542.424 us; speedup vs baseline: 1.2034x; 1.0566x over previous
//
#include <hip/hip_runtime.h>
#include <hip/hip_bf16.h>

// GraphConvLayer: out = relu(A_norm @ (X@W + b))
// R17 = R16 (Xf prepack, X->reg direct, A via LDS; 573us) + 2-deep pipeline:
//  - counted vmcnt(5): chunk c's 5 loads drained, chunk c+1's stay in flight
//  - X triple-buffered in regs (SSA), A triple-buffered in LDS (3x8KB)
//  - loads get TWO full phases of latency cover (was one + full drain)
//  - s_setprio(1) around MFMA clusters (T5; phase-split schedule -> pays)

#define NND    543
#define RPB    64
#define NTILES 9
#define NCH    9
#define BTOT   1024
#define GRID   (BTOT*NTILES)   // 9216, %8==0 -> bijective XCD swizzle

typedef __attribute__((ext_vector_type(8))) short short8;
typedef __attribute__((ext_vector_type(4))) float f32x4;

// ---- workspace ----
#define XF_BYTES ((size_t)BTOT*NCH*2048*16)   // 301,989,888 [bt][c][(fg*2+ks)*64+lane][16B]
#define MT_A     0                            // bf16 A-frags [tile9][c9][f8][lane64][16B] = 663552
#define MT_W     663552                       // bf16 W-frags [g16][ks8][lane64][16B] = 131072
#define MT_RS    794624                       // f32[576]
#define MT_BYTES 797184
#define WS_BIG   (XF_BYTES + (size_t)MT_BYTES)

// ---- LDS (bytes), main ----
// A bufs: 3 x 8KB at 0/8192/16384. Y bf16 [64][512B]=32KB overlays [0,32768) post-K.
#define LRS   32768         // f32[64]
#define LTOT  33280

#define GLD16(G, Ld) __builtin_amdgcn_global_load_lds( \
    (const __attribute__((address_space(1))) void*)(G), \
    (__attribute__((address_space(3))) void*)(Ld), 16, 0, 0)

__device__ __forceinline__ unsigned short f2bf(float f) {   // RNE f32 -> bf16 bits
  unsigned int u = __builtin_bit_cast(unsigned int, f);
  u += 0x7fffu + ((u >> 16) & 1u);
  return (unsigned short)(u >> 16);
}

// ---------------- prep: X -> bf16 B-fragment layout (proven R14) ----------------
__global__ void prep_xf(const float* __restrict__ x, char* __restrict__ xf) {
  __shared__ __align__(16) char xl[64 * 512];
  const int bc = blockIdx.x;                           // bt*NCH + c
  const int bt = bc / NCH, c = bc - bt * NCH;
  const int tid = threadIdx.x;                         // 256
  const float* xbt = x + (size_t)bt * (NND * 256);
  #pragma unroll
  for (int it = 0; it < 16; ++it) {
    const int slot = tid + (it << 8);
    const int r = slot >> 6, f4 = slot & 63;
    const int m = c * 64 + r;
    float4 v = make_float4(0.f, 0.f, 0.f, 0.f);
    if (m < NND) v = *(const float4*)(xbt + ((size_t)m << 8) + (f4 << 2));
    uint2 u;
    u.x = (unsigned)f2bf(v.x) | ((unsigned)f2bf(v.y) << 16);
    u.y = (unsigned)f2bf(v.z) | ((unsigned)f2bf(v.w) << 16);
    *(uint2*)(xl + (r << 9) + (f4 << 3)) = u;
  }
  __syncthreads();
  unsigned short* dst = (unsigned short*)xf + ((size_t)bc << 14);
  const unsigned short* src = (const unsigned short*)xl;
  #pragma unroll
  for (int it = 0; it < 8; ++it) {
    const int fi = tid + (it << 8);
    const int lane = fi & 63, ks = (fi >> 6) & 1, fg = fi >> 7;
    const int kl = ks * 32 + (lane >> 4) * 8;
    const int n = fg * 16 + (lane & 15);
    unsigned short tmp[8];
    #pragma unroll
    for (int e = 0; e < 8; ++e) tmp[e] = src[(kl + e) * 256 + n];
    *(uint4*)(dst + (size_t)fi * 8) = *(const uint4*)tmp;
  }
}

// ---------------- prep: A -> bf16 A-frags [tile][c][f=mt*2+ks][lane][16B] ----------------
__global__ void prep_a(const float* __restrict__ A, char* __restrict__ meta) {
  const int t = blockIdx.x * 256 + threadIdx.x;
  if (t >= NTILES * NCH * 8 * 64) return;
  const int lane = t & 63;
  const int f = (t >> 6) & 7;
  const int c = (t >> 9) % NCH;
  const int tile = t / (NCH * 8 * 64);
  const int mt = f >> 1, ks = f & 1;
  const int m = tile * 64 + mt * 16 + (lane & 15);
  const int kb = c * 64 + ks * 32 + (lane >> 4) * 8;
  unsigned short* dst = (unsigned short*)(meta + MT_A) + (size_t)t * 8;
  #pragma unroll
  for (int e = 0; e < 8; ++e) {
    const int k = kb + e;
    dst[e] = (m < NND && k < NND) ? f2bf(A[(size_t)m * NND + k]) : (unsigned short)0;
  }
}

// ---------------- prep: W -> bf16 B-frags ----------------
__global__ void prep_w(const float* __restrict__ W, char* __restrict__ meta) {
  const int t = blockIdx.x * 256 + threadIdx.x;
  if (t >= 16 * 8 * 64) return;
  const int lane = t & 63, ks = (t >> 6) & 7, g = t >> 9;
  const int krow = (lane >> 4) * 8, col = g * 16 + (lane & 15);
  unsigned short* dst = (unsigned short*)(meta + MT_W) + (size_t)t * 8;
  #pragma unroll
  for (int e = 0; e < 8; e++) dst[e] = f2bf(W[(ks * 32 + krow + e) * 256 + col]);
}

// ---------------- prep: rowsum ----------------
__global__ void prep_rs(const float* __restrict__ A, char* __restrict__ meta) {
  const int wid = (blockIdx.x * blockDim.x + threadIdx.x) >> 6;
  const int lane = threadIdx.x & 63;
  if (wid >= NTILES * RPB) return;
  float s = 0.f;
  if (wid < NND) {
    const float* arow = A + (size_t)wid * NND;
    for (int m = lane; m < NND; m += 64) s += arow[m];
  }
  #pragma unroll
  for (int o = 32; o > 0; o >>= 1) s += __shfl_xor(s, o);
  if (lane == 0) ((float*)(meta + MT_RS))[wid] = s;
}

// ---------------- main ----------------
__global__ __launch_bounds__(512, 2)
void gcn_main(const float* __restrict__ bias, float* __restrict__ out,
              const char* __restrict__ xfb, const char* __restrict__ meta)
{
  __shared__ __align__(16) char lds[LTOT];
  float* rsl = (float*)(lds + LRS);

  const int tid = threadIdx.x;
  const int w = tid >> 6, lane = tid & 63;
  const int cl = lane & 15, krow = (lane >> 4) * 8;

  const int p = blockIdx.x;
  const int L = (p & 7) * (GRID / 8) + (p >> 3);
  const int bt = L / NTILES;
  const int tile = L - bt * NTILES;
  const int n0 = tile * RPB;

  if (tid < RPB) rsl[tid] = ((const float*)(meta + MT_RS))[n0 + tid];

  // ======== GEMM1: Y = A_tile @ X ; 2-deep pipeline, counted vmcnt ========
  f32x4 acc[8];
  #pragma unroll
  for (int i = 0; i < 8; ++i) acc[i] = (f32x4){0.f, 0.f, 0.f, 0.f};

  const size_t xbase = ((size_t)(bt * NCH)) << 15;     // 32KB per (bt,c)
  const int xo00 = (((2 * w + 0) * 2 + 0) * 64 + lane) << 4;
  const int xo01 = (((2 * w + 0) * 2 + 1) * 64 + lane) << 4;
  const int xo10 = (((2 * w + 1) * 2 + 0) * 64 + lane) << 4;
  const int xo11 = (((2 * w + 1) * 2 + 1) * 64 + lane) << 4;
  const char* abase = meta + MT_A + ((size_t)(tile * NCH) << 13);  // 8KB per chunk

  // prologue: chunks 0 and 1 in flight (5 loads each, order: X0 A0 X1 A1)
  short8 xc00, xc01, xc10, xc11, xn00, xn01, xn10, xn11;
  {
    const char* x0 = xfb + xbase;
    xc00 = *(const short8*)(x0 + xo00);
    xc01 = *(const short8*)(x0 + xo01);
    xc10 = *(const short8*)(x0 + xo10);
    xc11 = *(const short8*)(x0 + xo11);
    GLD16(abase + (w << 10) + (lane << 4), lds + (w << 10));
    const char* x1 = xfb + xbase + (1 << 15);
    xn00 = *(const short8*)(x1 + xo00);
    xn01 = *(const short8*)(x1 + xo01);
    xn10 = *(const short8*)(x1 + xo10);
    xn11 = *(const short8*)(x1 + xo11);
    GLD16(abase + (1 << 13) + (w << 10) + (lane << 4), lds + 8192 + (w << 10));
  }

  #pragma unroll
  for (int c = 0; c < NCH; ++c) {
    // drain chunk c's 5 loads; chunk c+1's 5 stay in flight
    if (c < NCH - 1) asm volatile("s_waitcnt vmcnt(5)" ::: "memory");
    else             asm volatile("s_waitcnt vmcnt(0)" ::: "memory");
    __builtin_amdgcn_s_barrier();          // all waves' chunk-c data staged; buf (c+2)%3 free
    __builtin_amdgcn_sched_barrier(0);

    short8 xf00{}, xf01{}, xf10{}, xf11{};
    if (c + 2 < NCH) {                     // issue chunk c+2 (2 phases of cover)
      const char* x2 = xfb + xbase + ((size_t)(c + 2) << 15);
      xf00 = *(const short8*)(x2 + xo00);
      xf01 = *(const short8*)(x2 + xo01);
      xf10 = *(const short8*)(x2 + xo10);
      xf11 = *(const short8*)(x2 + xo11);
      GLD16(abase + ((size_t)(c + 2) << 13) + (w << 10) + (lane << 4),
            lds + ((c + 2) % 3) * 8192 + (w << 10));
    }
    __builtin_amdgcn_sched_barrier(0);     // pin issues above the MFMAs

    const char* ab = lds + (c % 3) * 8192;
    __builtin_amdgcn_s_setprio(1);
    {                                      // ks = 0
      const short8 a0 = *(const short8*)(ab + ((0 * 2 + 0) << 10) + (lane << 4));
      const short8 a1 = *(const short8*)(ab + ((1 * 2 + 0) << 10) + (lane << 4));
      const short8 a2 = *(const short8*)(ab + ((2 * 2 + 0) << 10) + (lane << 4));
      const short8 a3 = *(const short8*)(ab + ((3 * 2 + 0) << 10) + (lane << 4));
      acc[0] = __builtin_amdgcn_mfma_f32_16x16x32_bf16(a0, xc00, acc[0], 0, 0, 0);
      acc[1] = __builtin_amdgcn_mfma_f32_16x16x32_bf16(a0, xc10, acc[1], 0, 0, 0);
      acc[2] = __builtin_amdgcn_mfma_f32_16x16x32_bf16(a1, xc00, acc[2], 0, 0, 0);
      acc[3] = __builtin_amdgcn_mfma_f32_16x16x32_bf16(a1, xc10, acc[3], 0, 0, 0);
      acc[4] = __builtin_amdgcn_mfma_f32_16x16x32_bf16(a2, xc00, acc[4], 0, 0, 0);
      acc[5] = __builtin_amdgcn_mfma_f32_16x16x32_bf16(a2, xc10, acc[5], 0, 0, 0);
      acc[6] = __builtin_amdgcn_mfma_f32_16x16x32_bf16(a3, xc00, acc[6], 0, 0, 0);
      acc[7] = __builtin_amdgcn_mfma_f32_16x16x32_bf16(a3, xc10, acc[7], 0, 0, 0);
    }
    {                                      // ks = 1
      const short8 a0 = *(const short8*)(ab + ((0 * 2 + 1) << 10) + (lane << 4));
      const short8 a1 = *(const short8*)(ab + ((1 * 2 + 1) << 10) + (lane << 4));
      const short8 a2 = *(const short8*)(ab + ((2 * 2 + 1) << 10) + (lane << 4));
      const short8 a3 = *(const short8*)(ab + ((3 * 2 + 1) << 10) + (lane << 4));
      acc[0] = __builtin_amdgcn_mfma_f32_16x16x32_bf16(a0, xc01, acc[0], 0, 0, 0);
      acc[1] = __builtin_amdgcn_mfma_f32_16x16x32_bf16(a0, xc11, acc[1], 0, 0, 0);
      acc[2] = __builtin_amdgcn_mfma_f32_16x16x32_bf16(a1, xc01, acc[2], 0, 0, 0);
      acc[3] = __builtin_amdgcn_mfma_f32_16x16x32_bf16(a1, xc11, acc[3], 0, 0, 0);
      acc[4] = __builtin_amdgcn_mfma_f32_16x16x32_bf16(a2, xc01, acc[4], 0, 0, 0);
      acc[5] = __builtin_amdgcn_mfma_f32_16x16x32_bf16(a2, xc11, acc[5], 0, 0, 0);
      acc[6] = __builtin_amdgcn_mfma_f32_16x16x32_bf16(a3, xc01, acc[6], 0, 0, 0);
      acc[7] = __builtin_amdgcn_mfma_f32_16x16x32_bf16(a3, xc11, acc[7], 0, 0, 0);
    }
    __builtin_amdgcn_s_setprio(0);
    // rotate (SSA under full unroll)
    xc00 = xn00; xc01 = xn01; xc10 = xn10; xc11 = xn11;
    xn00 = xf00; xn01 = xf01; xn10 = xf10; xn11 = xf11;
  }
  __syncthreads();                         // A-bufs dead; region becomes Y

  // ---- Y -> LDS bf16 [64][512B], XOR-swizzled ----
  #pragma unroll
  for (int mt = 0; mt < 4; ++mt)
    #pragma unroll
    for (int nt = 0; nt < 2; ++nt)
      #pragma unroll
      for (int q = 0; q < 4; ++q) {
        const int row = mt * 16 + (lane >> 4) * 4 + q;   // C/D: col=lane&15, row=(lane>>4)*4+q
        const int col = w * 32 + nt * 16 + cl;
        *(unsigned short*)(lds + row * 512 + ((col * 2) ^ ((row & 7) << 4))) =
            f2bf(acc[mt * 2 + nt][q]);
      }
  __syncthreads();

  // ======== GEMM2: out_tile = relu(Y@W + rs*b); wave w owns cols [w*32, w*32+32) ========
  const char* wbase = meta + MT_W;
  const int gA = 2 * w;
  short8 wfA[8], wfB[8];
  #pragma unroll
  for (int ks = 0; ks < 8; ++ks) {
    wfA[ks] = *(const short8*)(wbase + (size_t)(((gA * 8 + ks) * 64 + lane) << 4));
    wfB[ks] = *(const short8*)(wbase + (size_t)((((gA + 1) * 8 + ks) * 64 + lane) << 4));
  }
  f32x4 aA[4], aB[4];
  #pragma unroll
  for (int mt = 0; mt < 4; ++mt) {
    aA[mt] = (f32x4){0.f, 0.f, 0.f, 0.f};
    aB[mt] = (f32x4){0.f, 0.f, 0.f, 0.f};
  }
  __builtin_amdgcn_s_setprio(1);
  #pragma unroll
  for (int ks = 0; ks < 8; ++ks) {
    #pragma unroll
    for (int mt = 0; mt < 4; ++mt) {
      const int r = mt * 16 + cl;
      const int kb = (ks * 64 + krow * 2) ^ ((r & 7) << 4);
      const short8 af = *(const short8*)(lds + r * 512 + kb);
      aA[mt] = __builtin_amdgcn_mfma_f32_16x16x32_bf16(af, wfA[ks], aA[mt], 0, 0, 0);
      aB[mt] = __builtin_amdgcn_mfma_f32_16x16x32_bf16(af, wfB[ks], aB[mt], 0, 0, 0);
    }
  }
  __builtin_amdgcn_s_setprio(0);
  __syncthreads();   // all waves done reading Y before bounce overlays it

  // ---- epilogue: bias + relu -> per-wave bounce -> full 128B-line dwordx4 stores ----
  float* wb = (float*)lds + w * (16 * 36);
  const int dA = w * 32 + cl;
  const float bvA = bias[dA], bvB = bias[dA + 16];
  #pragma unroll
  for (int mt = 0; mt < 4; ++mt) {
    #pragma unroll
    for (int q = 0; q < 4; ++q) {
      const int r16 = (lane >> 4) * 4 + q;
      const float rsv = rsl[mt * 16 + r16];
      wb[r16 * 36 + cl]      = fmaxf(aA[mt][q] + rsv * bvA, 0.f);
      wb[r16 * 36 + 16 + cl] = fmaxf(aB[mt][q] + rsv * bvB, 0.f);
    }
    asm volatile("s_waitcnt lgkmcnt(0)" ::: "memory");   // per-wave private region
    #pragma unroll
    for (int v = 0; v < 2; ++v) {
      const int i = lane * 2 + v;
      const int rI = i >> 3, cv = i & 7;
      const int n = n0 + mt * 16 + rI;
      if (n < NND)
        *(f32x4*)(out + ((size_t)bt * NND + n) * 256 + w * 32 + cv * 4) =
            *(const f32x4*)(wb + rI * 36 + cv * 4);
    }
  }
}

// ---------------- bare fallback (no workspace) ----------------
__global__ __launch_bounds__(512, 2)
void gcn_bare(const float* __restrict__ x, const float* __restrict__ Wm,
              const float* __restrict__ bias, const float* __restrict__ A,
              float* __restrict__ out)
{
  __shared__ __align__(16) char lds[33280];
  float* rsl = (float*)(lds + 32768);
  const int tid = threadIdx.x;
  const int w = tid >> 6, lane = tid & 63;
  const int cl = lane & 15, krow = (lane >> 4) * 8;
  const int p = blockIdx.x;
  const int L = (p & 7) * (GRID / 8) + (p >> 3);
  const int bt = L / NTILES;
  const int tile = L - bt * NTILES;
  const int n0 = tile * 64;
  const float* xbt = x + (size_t)bt * (NND * 256);

  for (int i = 0; i < 8; ++i) {
    const int r = w * 8 + i;
    const int n = n0 + r;
    f32x4 yv = (f32x4){0.f, 0.f, 0.f, 0.f};
    float s = 0.f;
    if (n < NND) {
      const float* arow = A + (size_t)n * NND;
      for (int m = 0; m < NND; ++m) {
        const float a = arow[m];
        s += a;
        if (a != 0.f) yv += a * *(const f32x4*)(xbt + (m << 8) + (lane << 2));
      }
    }
    if (lane == 0) rsl[r] = s;
    uint2 u;
    u.x = (unsigned)f2bf(yv.x) | ((unsigned)f2bf(yv.y) << 16);
    u.y = (unsigned)f2bf(yv.z) | ((unsigned)f2bf(yv.w) << 16);
    *(uint2*)(lds + r * 512 + ((lane * 8) ^ ((r & 7) << 4))) = u;
  }
  __syncthreads();

  const int gA = 2 * w;
  short8 wfA[8], wfB[8];
  #pragma unroll
  for (int ks = 0; ks < 8; ++ks)
    #pragma unroll
    for (int e = 0; e < 8; ++e) {
      wfA[ks][e] = (short)f2bf(Wm[(ks * 32 + krow + e) * 256 + gA * 16 + cl]);
      wfB[ks][e] = (short)f2bf(Wm[(ks * 32 + krow + e) * 256 + (gA + 1) * 16 + cl]);
    }
  f32x4 aA[4], aB[4];
  #pragma unroll
  for (int mt = 0; mt < 4; ++mt) {
    aA[mt] = (f32x4){0.f, 0.f, 0.f, 0.f};
    aB[mt] = (f32x4){0.f, 0.f, 0.f, 0.f};
  }
  #pragma unroll
  for (int ks = 0; ks < 8; ++ks)
    #pragma unroll
    for (int mt = 0; mt < 4; ++mt) {
      const int r = mt * 16 + cl;
      const int kb = (ks * 64 + krow * 2) ^ ((r & 7) << 4);
      const short8 af = *(const short8*)(lds + r * 512 + kb);
      aA[mt] = __builtin_amdgcn_mfma_f32_16x16x32_bf16(af, wfA[ks], aA[mt], 0, 0, 0);
      aB[mt] = __builtin_amdgcn_mfma_f32_16x16x32_bf16(af, wfB[ks], aB[mt], 0, 0, 0);
    }
  __syncthreads();

  float* wb = (float*)lds + w * (16 * 36);
  const int dA = w * 32 + cl;
  const float bvA = bias[dA], bvB = bias[dA + 16];
  #pragma unroll
  for (int mt = 0; mt < 4; ++mt) {
    #pragma unroll
    for (int q = 0; q < 4; ++q) {
      const int r16 = (lane >> 4) * 4 + q;
      const float rsv = rsl[mt * 16 + r16];
      wb[r16 * 36 + cl]      = fmaxf(aA[mt][q] + rsv * bvA, 0.f);
      wb[r16 * 36 + 16 + cl] = fmaxf(aB[mt][q] + rsv * bvB, 0.f);
    }
    asm volatile("s_waitcnt lgkmcnt(0)" ::: "memory");
    #pragma unroll
    for (int v = 0; v < 2; ++v) {
      const int i = lane * 2 + v;
      const int rI = i >> 3, cv = i & 7;
      const int n = n0 + mt * 16 + rI;
      if (n < NND)
        *(f32x4*)(out + ((size_t)bt * NND + n) * 256 + w * 32 + cv * 4) =
            *(const f32x4*)(wb + rI * 36 + cv * 4);
    }
  }
}

extern "C" void kernel_launch(void* const* d_in, const int* in_sizes, int n_in,
                              void* d_out, int out_size, void* d_ws, size_t ws_size,
                              hipStream_t stream) {
  const float* x  = (const float*)d_in[0];
  const float* Wm = (const float*)d_in[1];
  const float* b  = (const float*)d_in[2];
  const float* A  = (const float*)d_in[3];
  float* out = (float*)d_out;
  if (d_ws && ws_size >= WS_BIG) {
    char* xfp  = (char*)d_ws;
    char* meta = (char*)d_ws + XF_BYTES;
    prep_a<<<(NTILES * NCH * 8 * 64 + 255) / 256, 256, 0, stream>>>(A, meta);
    prep_w<<<(16 * 8 * 64 + 255) / 256, 256, 0, stream>>>(Wm, meta);
    prep_rs<<<(NTILES * RPB * 64 + 255) / 256, 256, 0, stream>>>(A, meta);
    prep_xf<<<BTOT * NCH, 256, 0, stream>>>(x, xfp);
    gcn_main<<<GRID, 512, 0, stream>>>(b, out, xfp, meta);
  } else {
    gcn_bare<<<GRID, 512, 0, stream>>>(x, Wm, b, A, out);
  }
}